// Round 2
// baseline (641.943 us; speedup 1.0000x reference)
//
#include <hip/hip_runtime.h>

#define THRESH 0.5f
#define BAND   1e-3f

constexpr int N  = 8192;   // rows of fea1 / fea2
constexpr int FD = 128;    // feature dim
constexpr int WD = 64;     // embed dim (= K of similarity GEMMs)
constexpr unsigned FIX_CAP = 16u << 20;  // 16M flagged entries max (64 MB in ws)

typedef __attribute__((ext_vector_type(8)))  short short8;   // 8 bf16 = 4 VGPR
typedef __attribute__((ext_vector_type(4)))  float f32x4;    // MFMA 16x16 accum

// f32 -> bf16 round-to-nearest-even (values are normal floats here)
static __device__ __forceinline__ unsigned short f2bf(float x) {
  union { float f; unsigned u; } v; v.f = x;
  unsigned r = v.u + 0x7FFFu + ((v.u >> 16) & 1u);
  return (unsigned short)(r >> 16);
}
static __device__ __forceinline__ float bf2f(unsigned short h) {
  union { unsigned u; float f; } v; v.u = (unsigned)h << 16;
  return v.f;
}

// ---------------------------------------------------------------------------
// Kernel 1: embed = fea @ w, row-normalize. Outputs f32 (for fixup) AND
// bf16 hi/lo split (for MFMA). grid (N/32, 2), block 256.
// ---------------------------------------------------------------------------
__global__ __launch_bounds__(256) void embed_norm(
    const float* __restrict__ fea1, const float* __restrict__ fea2,
    const float* __restrict__ w1,   const float* __restrict__ w2,
    float* __restrict__ E1n, float* __restrict__ E2n,
    unsigned short* __restrict__ E1h, unsigned short* __restrict__ E1l,
    unsigned short* __restrict__ E2h, unsigned short* __restrict__ E2l,
    unsigned* __restrict__ fix_cnt) {
  if (blockIdx.x == 0 && blockIdx.y == 0 && threadIdx.x == 0) *fix_cnt = 0;

  const int which = blockIdx.y;
  const float* __restrict__ fea = which ? fea2 : fea1;
  const float* __restrict__ w   = which ? w2   : w1;
  float*          En = which ? E2n : E1n;
  unsigned short* Eh = which ? E2h : E1h;
  unsigned short* El = which ? E2l : E1l;

  __shared__ float wl[FD * WD];   // 32 KB
  __shared__ float fl[32][FD];    // 16 KB

  const int t    = threadIdx.x;
  const int row0 = blockIdx.x * 32;

#pragma unroll
  for (int i = 0; i < 8; ++i) {
    const int idx = (t + i * 256) * 4;
    *(float4*)&wl[idx] = *(const float4*)&w[idx];
  }
#pragma unroll
  for (int i = 0; i < 4; ++i) {
    const int idx = t + i * 256;
    const int r = idx >> 5;
    const int c = (idx & 31) * 4;
    *(float4*)&fl[r][c] = *(const float4*)&fea[(size_t)(row0 + r) * FD + c];
  }
  __syncthreads();

  const int wave = t >> 6, lane = t & 63;
#pragma unroll 1
  for (int rr = 0; rr < 8; ++rr) {
    const int r = wave * 8 + rr;
    float acc = 0.f;
#pragma unroll 16
    for (int k = 0; k < FD; ++k)
      acc = fmaf(fl[r][k], wl[k * WD + lane], acc);
    float ss = acc * acc;
#pragma unroll
    for (int m = 32; m >= 1; m >>= 1) ss += __shfl_xor(ss, m, 64);
    const float scale = 1.f / fmaxf(sqrtf(ss), 1e-8f);
    const float e = acc * scale;
    const size_t o = (size_t)(row0 + r) * WD + lane;
    En[o] = e;
    const unsigned short h = f2bf(e);
    Eh[o] = h;
    El[o] = f2bf(e - bf2f(h));
  }
}

// ---------------------------------------------------------------------------
// Kernel 2: both planes via bf16 hi/lo MFMA, full compute (no symmetry —
// keeps ALL stores coalesced). 128x128 tile/block, 4 waves, 64x64 per wave,
// no LDS (fragments straight from L2/L3-resident 4 MB hi/lo arrays).
// Flags |sim-0.5| < BAND entries for exact-f32 fixup. grid (64,64), block 256.
// ---------------------------------------------------------------------------
__global__ __launch_bounds__(256) void sim_mfma(
    const unsigned short* __restrict__ E1h, const unsigned short* __restrict__ E1l,
    const unsigned short* __restrict__ E2h, const unsigned short* __restrict__ E2l,
    float* __restrict__ out,
    unsigned* __restrict__ fix_cnt, unsigned* __restrict__ fix_lst) {
  const int bi = blockIdx.y, bj = blockIdx.x;
  const int t = threadIdx.x, w = t >> 6, lane = t & 63;
  const int wr = w >> 1, wc = w & 1;
  const int row0 = bi * 128 + wr * 64;
  const int col0 = bj * 128 + wc * 64;
  const int fr = lane & 15;        // fragment row (A) / col (B)
  const int fg = lane >> 4;        // k-group / C row-group

#pragma unroll 1
  for (int plane = 0; plane < 2; ++plane) {
    const unsigned short* __restrict__ Bh = plane ? E1h : E2h;
    const unsigned short* __restrict__ Bl = plane ? E1l : E2l;

    f32x4 acc[4][4] = {};
#pragma unroll
    for (int ks = 0; ks < 2; ++ks) {
      const int koff = ks * 32 + fg * 8;        // k = ks*32 + (lane>>4)*8 + j
      short8 ah[4], al[4], bh[4], bl[4];
#pragma unroll
      for (int ti = 0; ti < 4; ++ti) {
        const size_t ra = (size_t)(row0 + ti * 16 + fr) * WD + koff;
        ah[ti] = *(const short8*)(E1h + ra);
        al[ti] = *(const short8*)(E1l + ra);
        const size_t rb = (size_t)(col0 + ti * 16 + fr) * WD + koff;
        bh[ti] = *(const short8*)(Bh + rb);
        bl[ti] = *(const short8*)(Bl + rb);
      }
#pragma unroll
      for (int ti = 0; ti < 4; ++ti)
#pragma unroll
        for (int tj = 0; tj < 4; ++tj) {
          acc[ti][tj] = __builtin_amdgcn_mfma_f32_16x16x32_bf16(ah[ti], bh[tj], acc[ti][tj], 0, 0, 0);
          acc[ti][tj] = __builtin_amdgcn_mfma_f32_16x16x32_bf16(ah[ti], bl[tj], acc[ti][tj], 0, 0, 0);
          acc[ti][tj] = __builtin_amdgcn_mfma_f32_16x16x32_bf16(al[ti], bh[tj], acc[ti][tj], 0, 0, 0);
          acc[ti][tj] = __builtin_amdgcn_mfma_f32_16x16x32_bf16(al[ti], bl[tj], acc[ti][tj], 0, 0, 0);
        }
    }

    float* __restrict__ o = out + (size_t)plane * N * N;
#pragma unroll
    for (int ti = 0; ti < 4; ++ti)
#pragma unroll
      for (int tj = 0; tj < 4; ++tj)
#pragma unroll
        for (int r = 0; r < 4; ++r) {
          const int R = row0 + ti * 16 + fg * 4 + r;   // C row = (lane>>4)*4+reg
          const int C = col0 + tj * 16 + fr;           // C col = lane&15
          const float v = acc[ti][tj][r];
          if (fabsf(v - THRESH) < BAND) {
            const unsigned idx = atomicAdd(fix_cnt, 1u);
            if (idx < FIX_CAP)
              fix_lst[idx] = ((unsigned)plane << 26) | ((unsigned)R << 13) | (unsigned)C;
          }
          o[(size_t)R * N + C] = (v < THRESH) ? 0.f : v;
        }
  }
}

// ---------------------------------------------------------------------------
// Kernel 3: exact f32 recompute of borderline entries (same fmaf k-order that
// matched jax exactly, absmax 0.0). Fixed launch config, grid-stride.
// ---------------------------------------------------------------------------
__global__ __launch_bounds__(256) void fixup(
    const float* __restrict__ E1, const float* __restrict__ E2,
    float* __restrict__ out,
    const unsigned* __restrict__ fix_cnt, const unsigned* __restrict__ fix_lst) {
  unsigned n = *fix_cnt;
  if (n > FIX_CAP) n = FIX_CAP;
  for (unsigned idx = blockIdx.x * blockDim.x + threadIdx.x; idx < n;
       idx += gridDim.x * blockDim.x) {
    const unsigned e = fix_lst[idx];
    const int plane = (int)(e >> 26);
    const int i = (int)((e >> 13) & 8191);
    const int j = (int)(e & 8191);
    const float* __restrict__ B = plane ? E1 : E2;
    float s = 0.f;
#pragma unroll 16
    for (int k = 0; k < WD; ++k)
      s = fmaf(E1[i * WD + k], B[j * WD + k], s);
    out[(size_t)plane * N * N + (size_t)i * N + j] = (s < THRESH) ? 0.f : s;
  }
}

extern "C" void kernel_launch(void* const* d_in, const int* in_sizes, int n_in,
                              void* d_out, int out_size, void* d_ws, size_t ws_size,
                              hipStream_t stream) {
  const float* fea1 = (const float*)d_in[0];
  const float* fea2 = (const float*)d_in[1];
  const float* w1   = (const float*)d_in[2];
  const float* w2   = (const float*)d_in[3];
  float* out = (float*)d_out;

  char* ws = (char*)d_ws;
  float*          E1n = (float*)(ws);                         // 2 MB
  float*          E2n = (float*)(ws + (2u << 20));            // 2 MB
  unsigned short* E1h = (unsigned short*)(ws + (4u << 20));   // 1 MB
  unsigned short* E1l = (unsigned short*)(ws + (5u << 20));   // 1 MB
  unsigned short* E2h = (unsigned short*)(ws + (6u << 20));   // 1 MB
  unsigned short* E2l = (unsigned short*)(ws + (7u << 20));   // 1 MB
  unsigned*   fix_cnt = (unsigned*)(ws + (8u << 20));
  unsigned*   fix_lst = (unsigned*)(ws + (8u << 20) + 256);   // 64 MB cap

  embed_norm<<<dim3(N / 32, 2), 256, 0, stream>>>(
      fea1, fea2, w1, w2, E1n, E2n, E1h, E1l, E2h, E2l, fix_cnt);
  sim_mfma<<<dim3(64, 64), 256, 0, stream>>>(
      E1h, E1l, E2h, E2l, out, fix_cnt, fix_lst);
  fixup<<<64, 256, 0, stream>>>(E1n, E2n, out, fix_cnt, fix_lst);
}

// Round 4
// 618.833 us; speedup vs baseline: 1.0373x; 1.0373x over previous
//
#include <hip/hip_runtime.h>

#define THRESH 0.5f
#define BAND   1e-3f

constexpr int N  = 8192;   // rows of fea1 / fea2
constexpr int FD = 128;    // feature dim
constexpr int WD = 64;     // embed dim (= K of similarity GEMMs)

typedef __attribute__((ext_vector_type(8)))  short short8;   // 8 bf16 = 4 VGPR
typedef __attribute__((ext_vector_type(4)))  float f32x4;    // MFMA 16x16 accum / stores

// f32 -> bf16 round-to-nearest-even
static __device__ __forceinline__ unsigned short f2bf(float x) {
  union { float f; unsigned u; } v; v.f = x;
  unsigned r = v.u + 0x7FFFu + ((v.u >> 16) & 1u);
  return (unsigned short)(r >> 16);
}
static __device__ __forceinline__ float bf2f(unsigned short h) {
  union { unsigned u; float f; } v; v.u = (unsigned)h << 16;
  return v.f;
}

// Exact f32 dot, same sequential fmaf k-order as the reference-matching path.
// noinline: called only for ~1e3 borderline entries; keeps main loop code small.
static __device__ __noinline__ float exact_dot(const float* __restrict__ a,
                                               const float* __restrict__ b) {
  float s = 0.f;
#pragma unroll 1
  for (int k = 0; k < WD; ++k) s = fmaf(a[k], b[k], s);
  return s;
}

// ---------------------------------------------------------------------------
// Kernel 1: embed = fea @ w, row-normalize. Outputs f32 (for exact fixup) AND
// bf16 hi/lo split (for MFMA). grid (N/32, 2), block 256.
// ---------------------------------------------------------------------------
__global__ __launch_bounds__(256) void embed_norm(
    const float* __restrict__ fea1, const float* __restrict__ fea2,
    const float* __restrict__ w1,   const float* __restrict__ w2,
    float* __restrict__ E1n, float* __restrict__ E2n,
    unsigned short* __restrict__ E1h, unsigned short* __restrict__ E1l,
    unsigned short* __restrict__ E2h, unsigned short* __restrict__ E2l) {
  const int which = blockIdx.y;
  const float* __restrict__ fea = which ? fea2 : fea1;
  const float* __restrict__ w   = which ? w2   : w1;
  float*          En = which ? E2n : E1n;
  unsigned short* Eh = which ? E2h : E1h;
  unsigned short* El = which ? E2l : E1l;

  __shared__ float wl[FD * WD];   // 32 KB
  __shared__ float fl[32][FD];    // 16 KB

  const int t    = threadIdx.x;
  const int row0 = blockIdx.x * 32;

#pragma unroll
  for (int i = 0; i < 8; ++i) {
    const int idx = (t + i * 256) * 4;
    *(float4*)&wl[idx] = *(const float4*)&w[idx];
  }
#pragma unroll
  for (int i = 0; i < 4; ++i) {
    const int idx = t + i * 256;
    const int r = idx >> 5;
    const int c = (idx & 31) * 4;
    *(float4*)&fl[r][c] = *(const float4*)&fea[(size_t)(row0 + r) * FD + c];
  }
  __syncthreads();

  const int wave = t >> 6, lane = t & 63;
#pragma unroll 1
  for (int rr = 0; rr < 8; ++rr) {
    const int r = wave * 8 + rr;
    float acc = 0.f;
#pragma unroll 16
    for (int k = 0; k < FD; ++k)
      acc = fmaf(fl[r][k], wl[k * WD + lane], acc);
    float ss = acc * acc;
#pragma unroll
    for (int m = 32; m >= 1; m >>= 1) ss += __shfl_xor(ss, m, 64);
    const float scale = 1.f / fmaxf(sqrtf(ss), 1e-8f);
    const float e = acc * scale;
    const size_t o = (size_t)(row0 + r) * WD + lane;
    En[o] = e;
    const unsigned short h = f2bf(e);
    Eh[o] = h;
    El[o] = f2bf(e - bf2f(h));
  }
}

// ---------------------------------------------------------------------------
// Kernel 2: both planes via bf16 hi/lo MFMA with SWAPPED operands so each
// lane's 4 accum regs are 4 consecutive C-columns in ONE row -> f32x4
// nontemporal stores. Y (=E1-row) fragments reused across both planes.
// Borderline |v-0.5|<BAND entries recomputed inline in exact f32.
// 128x128 tile/block, 4 waves of 64x64. grid (64,64), block 256. No LDS.
// ---------------------------------------------------------------------------
__global__ __launch_bounds__(256) void sim_mfma(
    const unsigned short* __restrict__ E1h, const unsigned short* __restrict__ E1l,
    const unsigned short* __restrict__ E2h, const unsigned short* __restrict__ E2l,
    const float* __restrict__ E1n, const float* __restrict__ E2n,
    float* __restrict__ out) {
  const int bi = blockIdx.y, bj = blockIdx.x;
  const int t = threadIdx.x, w = t >> 6, lane = t & 63;
  const int wr = w >> 1, wc = w & 1;
  const int row0 = bi * 128 + wr * 64;   // m range (C rows, E1 side)
  const int col0 = bj * 128 + wc * 64;   // n range (C cols, E2/E1 side)
  const int fr = lane & 15;
  const int fg = lane >> 4;

  // Y fragments (b-operand): E1 rows row0+ti*16+fr, k = ks*32 + fg*8.
  // Same for both planes -> load once.
  short8 yh[2][4], yl[2][4];
#pragma unroll
  for (int ks = 0; ks < 2; ++ks)
#pragma unroll
    for (int ti = 0; ti < 4; ++ti) {
      const size_t r = (size_t)(row0 + ti * 16 + fr) * WD + ks * 32 + fg * 8;
      yh[ks][ti] = *(const short8*)(E1h + r);
      yl[ks][ti] = *(const short8*)(E1l + r);
    }

#pragma unroll 1
  for (int plane = 0; plane < 2; ++plane) {
    const unsigned short* __restrict__ Xh = plane ? E1h : E2h;
    const unsigned short* __restrict__ Xl = plane ? E1l : E2l;
    const float*          __restrict__ Xn = plane ? E1n : E2n;

    f32x4 acc[4][4] = {};   // [tj (n-tile)][ti (m-tile)]
#pragma unroll
    for (int ks = 0; ks < 2; ++ks) {
      short8 xh[4], xl[4];
#pragma unroll
      for (int tj = 0; tj < 4; ++tj) {
        const size_t r = (size_t)(col0 + tj * 16 + fr) * WD + ks * 32 + fg * 8;
        xh[tj] = *(const short8*)(Xh + r);
        xl[tj] = *(const short8*)(Xl + r);
      }
#pragma unroll
      for (int tj = 0; tj < 4; ++tj)
#pragma unroll
        for (int ti = 0; ti < 4; ++ti) {
          acc[tj][ti] = __builtin_amdgcn_mfma_f32_16x16x32_bf16(xh[tj], yh[ks][ti], acc[tj][ti], 0, 0, 0);
          acc[tj][ti] = __builtin_amdgcn_mfma_f32_16x16x32_bf16(xh[tj], yl[ks][ti], acc[tj][ti], 0, 0, 0);
          acc[tj][ti] = __builtin_amdgcn_mfma_f32_16x16x32_bf16(xl[tj], yh[ks][ti], acc[tj][ti], 0, 0, 0);
          acc[tj][ti] = __builtin_amdgcn_mfma_f32_16x16x32_bf16(xl[tj], yl[ks][ti], acc[tj][ti], 0, 0, 0);
        }
    }

    // Epilogue: computed C^T fragment, so reg r holds C[m][nb+r] -> f32x4/lane.
    float* __restrict__ o = out + (size_t)plane * N * N;
#pragma unroll
    for (int tj = 0; tj < 4; ++tj)
#pragma unroll
      for (int ti = 0; ti < 4; ++ti) {
        const int m  = row0 + ti * 16 + fr;
        const int nb = col0 + tj * 16 + fg * 4;
        const f32x4 v = acc[tj][ti];
        f32x4 sv;
#pragma unroll
        for (int r = 0; r < 4; ++r) {
          float val = v[r];
          if (fabsf(val - THRESH) < BAND)   // rare: exact f32 recompute
            val = exact_dot(E1n + (size_t)m * WD, Xn + (size_t)(nb + r) * WD);
          sv[r] = (val < THRESH) ? 0.f : val;
        }
        __builtin_nontemporal_store(sv, (f32x4*)(o + (size_t)m * N + nb));
      }
  }
}

extern "C" void kernel_launch(void* const* d_in, const int* in_sizes, int n_in,
                              void* d_out, int out_size, void* d_ws, size_t ws_size,
                              hipStream_t stream) {
  const float* fea1 = (const float*)d_in[0];
  const float* fea2 = (const float*)d_in[1];
  const float* w1   = (const float*)d_in[2];
  const float* w2   = (const float*)d_in[3];
  float* out = (float*)d_out;

  char* ws = (char*)d_ws;
  float*          E1n = (float*)(ws);                         // 2 MB
  float*          E2n = (float*)(ws + (2u << 20));            // 2 MB
  unsigned short* E1h = (unsigned short*)(ws + (4u << 20));   // 1 MB
  unsigned short* E1l = (unsigned short*)(ws + (5u << 20));   // 1 MB
  unsigned short* E2h = (unsigned short*)(ws + (6u << 20));   // 1 MB
  unsigned short* E2l = (unsigned short*)(ws + (7u << 20));   // 1 MB

  embed_norm<<<dim3(N / 32, 2), 256, 0, stream>>>(
      fea1, fea2, w1, w2, E1n, E2n, E1h, E1l, E2h, E2l);
  sim_mfma<<<dim3(64, 64), 256, 0, stream>>>(
      E1h, E1l, E2h, E2l, E1n, E2n, out);
}